// Round 1
// 224.552 us; speedup vs baseline: 1.1170x; 1.1170x over previous
//
#include <hip/hip_runtime.h>
#include <math.h>

// Problem constants
#define N    130
#define NN   (130*130)       // 16900
#define NNN  (130*130*130)   // 2197000
#define NCH  12
#define XN   128
#define XNN  (XN*XN)

// Fused-kernel tiling
#define WT   5               // w tiles (32 each, last partially valid)
#define HT   11              // h tiles (12 output rows each, 16 W rows computed)
#define DSEGS 10             // d segments (13 output planes each)
#define DLEN 13
#define STEPS 17             // DLEN + 4 warmup planes

typedef float f32x4 __attribute__((ext_vector_type(4)));

// ---------------------------------------------------------------------------
// Fused kernel: conv-diff^2 + 5x5x5 replicated box + channel min/mean.
//
// The 12 channels are the 12 orthogonal pairs of 6 shared neighbour values
//   Y0=d-, Y1=d+, Y2=h-, Y3=h+, Y4=w-, Y5=w+   (dilation-2 face neighbours)
// Per-dim addressing in box coords c in [0,129] (verified vs SH tables):
//   class  1 (center): ix = clamp(c-1,0,127), always valid
//   class -1:          ix = clamp(c-3,0,127), masked iff c==0
//   class  3:          ix = clamp(c+1,0,127), masked iff c==129
// Channel pairs (order matches reference):
//   0:(Y4,Y0) 1:(Y2,Y0) 2:(Y2,Y4) 3:(Y5,Y0) 4:(Y5,Y2) 5:(Y1,Y4)
//   6:(Y1,Y2) 7:(Y1,Y5) 8:(Y3,Y0) 9:(Y3,Y4) 10:(Y3,Y5) 11:(Y3,Y1)
//
// Block = 512 threads (32 w-lanes x 16 h-rows). Each step (one d box-plane):
//   - every thread computes W[12] = Box_w(diff^2) for its (h,w)
//   - LDS exchange (f32x4 x3, contiguous-per-lane => conflict-free)
//   - interior rows (r in [2,14)) sum 5 h-taps -> HW, push into 5-slot
//     register ring (static slots), and once the ring is full emit
//     ssd -> mind for output plane d = bd-2.
// ---------------------------------------------------------------------------
__global__ __launch_bounds__(512) void k_fused(const float* __restrict__ x,
                                               float* __restrict__ Cout,
                                               double* __restrict__ acc) {
    const int tid = threadIdx.x;
    const int wl  = tid & 31;
    const int r   = tid >> 5;

    const int b    = blockIdx.x;
    const int wt   = b % WT;
    const int rest = b / WT;
    const int ht   = rest % HT;
    const int ds   = rest / HT;

    const int W0 = wt * 32;
    const int H0 = ht * 12;
    const int D0 = ds * DLEN;

    const int  w_out = W0 + wl;
    const int  wc    = min(w_out, 129);                 // clamp garbage lanes
    const int  ghW   = min(max(H0 - 2 + r, 0), 129);    // W row (replicated)
    const int  oh    = H0 + r - 2;                      // output row (interior)
    const bool interior = (r >= 2) && (r < 14);
    const bool valid    = interior && (oh < N) && (w_out < N);

    // h-dim precompute (thread-invariant)
    const int   ih_c = min(max(ghW - 1, 0), 127);
    const int   ih_m = min(max(ghW - 3, 0), 127);
    const int   ih_p = min(ghW + 1, 127);
    const float fhm  = (ghW >= 1)   ? 1.0f : 0.0f;
    const float fhp  = (ghW <= 128) ? 1.0f : 0.0f;
    const int   dhm  = (ih_m - ih_c) * XN;
    const int   dhp  = (ih_p - ih_c) * XN;

    // w-dim per-tap precompute (thread-invariant)
    int   oc[5], o4[5], o5[5];
    float fwm[5], fwp[5];
    #pragma unroll
    for (int j = 0; j < 5; ++j) {
        const int cw = min(max(wc + j - 2, 0), 129);
        oc[j] = ih_c * XN + min(max(cw - 1, 0), 127);
        o4[j] = ih_c * XN + min(max(cw - 3, 0), 127);
        o5[j] = ih_c * XN + min(cw + 1, 127);
        fwm[j] = (cw >= 1)   ? 1.0f : 0.0f;
        fwp[j] = (cw <= 128) ? 1.0f : 0.0f;
    }

    __shared__ f32x4 Wlds[3][16][32];   // [ch-group][row][lane], 24 KB
    __shared__ float red[512];

    f32x4 ring[5][3];                   // 5-deep d ring, 12 ch as 3x f32x4
    float lsum   = 0.0f;
    int   voxoff = D0 * NN + oh * N + w_out;   // element offset of next output

#define STEP(IT, SLOT, DOUT) do {                                             \
    const int bd = D0 - 2 + (IT);                                             \
    const int dc = min(max(bd, 0), 129);                                      \
    const float* pc = x + (size_t)(min(max(dc - 1, 0), 127)) * XNN;           \
    const float* pm = x + (size_t)(min(max(dc - 3, 0), 127)) * XNN;           \
    const float* pp = x + (size_t)(min(dc + 1, 127)) * XNN;                   \
    const float fdm = (dc >= 1)   ? 1.0f : 0.0f;                              \
    const float fdp = (dc <= 128) ? 1.0f : 0.0f;                              \
    float Wa[12];                                                             \
    _Pragma("unroll") for (int z = 0; z < 12; ++z) Wa[z] = 0.0f;              \
    _Pragma("unroll") for (int j = 0; j < 5; ++j) {                           \
        const float y0 = pm[oc[j]]       * fdm;                               \
        const float y1 = pp[oc[j]]       * fdp;                               \
        const float y2 = pc[oc[j] + dhm] * fhm;                               \
        const float y3 = pc[oc[j] + dhp] * fhp;                               \
        const float y4 = pc[o4[j]]       * fwm[j];                            \
        const float y5 = pc[o5[j]]       * fwp[j];                            \
        float t;                                                              \
        t = y4 - y0; Wa[0]  += t * t;  t = y2 - y0; Wa[1]  += t * t;          \
        t = y2 - y4; Wa[2]  += t * t;  t = y5 - y0; Wa[3]  += t * t;          \
        t = y5 - y2; Wa[4]  += t * t;  t = y1 - y4; Wa[5]  += t * t;          \
        t = y1 - y2; Wa[6]  += t * t;  t = y1 - y5; Wa[7]  += t * t;          \
        t = y3 - y0; Wa[8]  += t * t;  t = y3 - y4; Wa[9]  += t * t;          \
        t = y3 - y5; Wa[10] += t * t;  t = y3 - y1; Wa[11] += t * t;          \
    }                                                                         \
    __syncthreads();                    /* WAR: previous step's reads done */ \
    Wlds[0][r][wl] = (f32x4){Wa[0], Wa[1], Wa[2],  Wa[3]};                    \
    Wlds[1][r][wl] = (f32x4){Wa[4], Wa[5], Wa[6],  Wa[7]};                    \
    Wlds[2][r][wl] = (f32x4){Wa[8], Wa[9], Wa[10], Wa[11]};                   \
    __syncthreads();                                                          \
    if (interior) {                                                           \
        _Pragma("unroll") for (int g = 0; g < 3; ++g) {                       \
            f32x4 a = Wlds[g][r - 2][wl];                                     \
            a += Wlds[g][r - 1][wl];                                          \
            a += Wlds[g][r    ][wl];                                          \
            a += Wlds[g][r + 1][wl];                                          \
            a += Wlds[g][r + 2][wl];                                          \
            ring[SLOT][g] = a;                                                \
        }                                                                     \
        if (DOUT) {                                                           \
            f32x4 sg[3];                                                      \
            _Pragma("unroll") for (int g = 0; g < 3; ++g) {                   \
                f32x4 a = ring[0][g];                                         \
                a += ring[1][g]; a += ring[2][g];                             \
                a += ring[3][g]; a += ring[4][g];                             \
                sg[g] = a * (1.0f / 125.0f);                                  \
            }                                                                 \
            float sv[12];                                                     \
            _Pragma("unroll") for (int g = 0; g < 3; ++g) {                   \
                sv[4*g+0] = sg[g].x; sv[4*g+1] = sg[g].y;                     \
                sv[4*g+2] = sg[g].z; sv[4*g+3] = sg[g].w;                     \
            }                                                                 \
            float mn = sv[0], tt = sv[0];                                     \
            _Pragma("unroll") for (int z = 1; z < 12; ++z) {                  \
                mn = fminf(mn, sv[z]); tt += sv[z];                           \
            }                                                                 \
            if (valid) {                                                      \
                _Pragma("unroll") for (int z = 0; z < 12; ++z)                \
                    Cout[(size_t)z * NNN + (unsigned)voxoff] = sv[z] - mn;    \
                lsum += tt * (1.0f / 12.0f) - mn;                             \
                voxoff += NN;                                                 \
            }                                                                 \
        }                                                                     \
    }                                                                         \
} while (0)

    // warmup: fill ring slots 0..3 (box planes D0-2 .. D0+1, clamped)
    STEP(0, 0, false);
    STEP(1, 1, false);
    STEP(2, 2, false);
    STEP(3, 3, false);

    // main: its 4..16, slot = it % 5 kept compile-time (base ≡ 4 mod 5)
    for (int base = 4; base < STEPS; base += 5) {
        STEP(base + 0, 4, true);
        if (base + 1 < STEPS) STEP(base + 1, 0, true);
        if (base + 2 < STEPS) STEP(base + 2, 1, true);
        if (base + 3 < STEPS) STEP(base + 3, 2, true);
        if (base + 4 < STEPS) STEP(base + 4, 3, true);
    }
#undef STEP

    // block reduction of mind_var partial sum
    red[tid] = lsum;
    __syncthreads();
    for (int st = 256; st > 0; st >>= 1) {
        if (tid < st) red[tid] += red[tid + st];
        __syncthreads();
    }
    if (tid == 0) atomicAdd(acc, (double)red[0]);
}

// zero the accumulator
__global__ void k_zero(double* acc) {
    if (blockIdx.x == 0 && threadIdx.x == 0) *acc = 0.0;
}

// K3: in-place epilogue on d_out. mvar = mean_ch(mind), clip, exp.
__global__ __launch_bounds__(256) void k_exp(float* __restrict__ io,
                                             const double* __restrict__ acc) {
    int q = blockIdx.x * 256 + threadIdx.x;
    if (q >= NNN) return;
    float mv_mean = (float)(*acc * (1.0 / (double)NNN));
    float v[NCH];
    float tot = 0.0f;
    #pragma unroll
    for (int o = 0; o < NCH; ++o) {
        v[o] = io[(size_t)o * NNN + q];
        tot += v[o];
    }
    float mvar = tot * (1.0f / 12.0f);
    mvar = fminf(fmaxf(mvar, mv_mean * 0.001f), mv_mean * 1000.0f);
    float inv = 1.0f / mvar;
    #pragma unroll
    for (int o = 0; o < NCH; ++o)
        io[(size_t)o * NNN + q] = expf(-v[o] * inv);
}

extern "C" void kernel_launch(void* const* d_in, const int* in_sizes, int n_in,
                              void* d_out, int out_size, void* d_ws, size_t ws_size,
                              hipStream_t stream) {
    const float* x = (const float*)d_in[0];
    float* out = (float*)d_out;                 // [12,130,130,130] f32
    double* acc = (double*)d_ws;

    k_zero <<<1, 64, 0, stream>>>(acc);
    k_fused<<<WT * HT * DSEGS, 512, 0, stream>>>(x, out, acc);   // 550 blocks
    k_exp  <<<(NNN + 255) / 256, 256, 0, stream>>>(out, acc);
}

// Round 2
// 212.795 us; speedup vs baseline: 1.1787x; 1.0552x over previous
//
#include <hip/hip_runtime.h>
#include <math.h>

// Problem constants
#define N    130
#define NN   (130*130)       // 16900
#define NNN  (130*130*130)   // 2197000
#define NQ4  (NNN/4)         // 549250
#define NCH  12
#define XN   128
#define XNN  (XN*XN)

// Fused-kernel tiling
#define WT   5               // w tiles (32 lanes each, last partially valid)
#define HT   11              // h tiles (12 output rows each, 16 W rows computed)
#define DSEGS 9              // d segments, balanced: grid = 5*11*9 = 495 <= 512
                             // co-resident blocks (2/CU at 96 VGPR) -> no tail

typedef float f32x4 __attribute__((ext_vector_type(4)));

// ---------------------------------------------------------------------------
// Fused kernel: conv-diff^2 + 5x5x5 replicated box + channel min/mean.
//
// The 12 channels are the 12 orthogonal pairs of 6 shared neighbour values
//   Y0=d-, Y1=d+, Y2=h-, Y3=h+, Y4=w-, Y5=w+   (dilation-2 face neighbours)
// Per-dim addressing in box coords c in [0,129] (verified vs SH tables):
//   class  1 (center): ix = clamp(c-1,0,127), always valid
//   class -1:          ix = clamp(c-3,0,127), masked iff c==0
//   class  3:          ix = clamp(c+1,0,127), masked iff c==129
// Channel pairs (order matches reference):
//   0:(Y4,Y0) 1:(Y2,Y0) 2:(Y2,Y4) 3:(Y5,Y0) 4:(Y5,Y2) 5:(Y1,Y4)
//   6:(Y1,Y2) 7:(Y1,Y5) 8:(Y3,Y0) 9:(Y3,Y4) 10:(Y3,Y5) 11:(Y3,Y1)
//
// Block = 512 threads (32 w-lanes x 16 h-rows), walks d through its segment.
// Per step (one d box-plane): W-box diff^2 for all 12 channels, LDS plane
// exchange (double-buffered, ONE barrier per step), 5-tap h-sum, 5-deep
// register ring along d (static slots), emit mind directly.
// ---------------------------------------------------------------------------
__global__ __launch_bounds__(512) void k_fused(const float* __restrict__ x,
                                               float* __restrict__ Cout,
                                               double* __restrict__ acc) {
    const int tid = threadIdx.x;
    const int wl  = tid & 31;
    const int r   = tid >> 5;

    const int b    = blockIdx.x;
    const int wt   = b % WT;
    const int rest = b / WT;
    const int ht   = rest % HT;
    const int ds   = rest / HT;

    const int W0 = wt * 32;
    const int H0 = ht * 12;
    const int D0 = (ds * 130) / DSEGS;          // balanced d split
    const int D1 = ((ds + 1) * 130) / DSEGS;
    const int steps = (D1 - D0) + 4;            // 18 or 19

    const int  w_out = W0 + wl;
    const int  wc    = min(w_out, 129);                 // clamp garbage lanes
    const int  ghW   = min(max(H0 - 2 + r, 0), 129);    // W row (replicated)
    const int  oh    = H0 + r - 2;                      // output row (interior)
    const bool interior = (r >= 2) && (r < 14);
    const bool valid    = interior && (oh < N) && (w_out < N);

    // h-dim precompute (thread-invariant)
    const int   ih_c = min(max(ghW - 1, 0), 127);
    const int   ih_m = min(max(ghW - 3, 0), 127);
    const int   ih_p = min(ghW + 1, 127);
    const float fhm  = (ghW >= 1)   ? 1.0f : 0.0f;
    const float fhp  = (ghW <= 128) ? 1.0f : 0.0f;
    const int   dhm  = (ih_m - ih_c) * XN;
    const int   dhp  = (ih_p - ih_c) * XN;

    // w-dim per-tap precompute (thread-invariant)
    int   oc[5], o4[5], o5[5];
    float fwm[5], fwp[5];
    #pragma unroll
    for (int j = 0; j < 5; ++j) {
        const int cw = min(max(wc + j - 2, 0), 129);
        oc[j] = ih_c * XN + min(max(cw - 1, 0), 127);
        o4[j] = ih_c * XN + min(max(cw - 3, 0), 127);
        o5[j] = ih_c * XN + min(cw + 1, 127);
        fwm[j] = (cw >= 1)   ? 1.0f : 0.0f;
        fwp[j] = (cw <= 128) ? 1.0f : 0.0f;
    }

    __shared__ f32x4 Wlds[2][3][16][32];   // double-buffered plane, 48 KB
    __shared__ float red[512];

    f32x4 ring[5][3];                   // 5-deep d ring, 12 ch as 3x f32x4
    float lsum   = 0.0f;
    int   voxoff = D0 * NN + oh * N + w_out;   // element offset of next output

#define STEP(IT, SLOT, DOUT) do {                                             \
    const int it_ = (IT);                                                     \
    const int bd = D0 - 2 + it_;                                              \
    const int dc = min(max(bd, 0), 129);                                      \
    const float* pc = x + (size_t)(min(max(dc - 1, 0), 127)) * XNN;           \
    const float* pm = x + (size_t)(min(max(dc - 3, 0), 127)) * XNN;           \
    const float* pp = x + (size_t)(min(dc + 1, 127)) * XNN;                   \
    const float fdm = (dc >= 1)   ? 1.0f : 0.0f;                              \
    const float fdp = (dc <= 128) ? 1.0f : 0.0f;                              \
    float Wa[12];                                                             \
    _Pragma("unroll") for (int z = 0; z < 12; ++z) Wa[z] = 0.0f;              \
    _Pragma("unroll") for (int j = 0; j < 5; ++j) {                           \
        const float y0 = pm[oc[j]]       * fdm;                               \
        const float y1 = pp[oc[j]]       * fdp;                               \
        const float y2 = pc[oc[j] + dhm] * fhm;                               \
        const float y3 = pc[oc[j] + dhp] * fhp;                               \
        const float y4 = pc[o4[j]]       * fwm[j];                            \
        const float y5 = pc[o5[j]]       * fwp[j];                            \
        float t;                                                              \
        t = y4 - y0; Wa[0]  += t * t;  t = y2 - y0; Wa[1]  += t * t;          \
        t = y2 - y4; Wa[2]  += t * t;  t = y5 - y0; Wa[3]  += t * t;          \
        t = y5 - y2; Wa[4]  += t * t;  t = y1 - y4; Wa[5]  += t * t;          \
        t = y1 - y2; Wa[6]  += t * t;  t = y1 - y5; Wa[7]  += t * t;          \
        t = y3 - y0; Wa[8]  += t * t;  t = y3 - y4; Wa[9]  += t * t;          \
        t = y3 - y5; Wa[10] += t * t;  t = y3 - y1; Wa[11] += t * t;          \
    }                                                                         \
    const int pb = it_ & 1;                                                   \
    Wlds[pb][0][r][wl] = (f32x4){Wa[0], Wa[1], Wa[2],  Wa[3]};                \
    Wlds[pb][1][r][wl] = (f32x4){Wa[4], Wa[5], Wa[6],  Wa[7]};                \
    Wlds[pb][2][r][wl] = (f32x4){Wa[8], Wa[9], Wa[10], Wa[11]};               \
    __syncthreads();   /* WAR on pb covered by previous step's barrier */     \
    if (interior) {                                                           \
        _Pragma("unroll") for (int g = 0; g < 3; ++g) {                       \
            f32x4 a = Wlds[pb][g][r - 2][wl];                                 \
            a += Wlds[pb][g][r - 1][wl];                                      \
            a += Wlds[pb][g][r    ][wl];                                      \
            a += Wlds[pb][g][r + 1][wl];                                      \
            a += Wlds[pb][g][r + 2][wl];                                      \
            ring[SLOT][g] = a;                                                \
        }                                                                     \
        if (DOUT) {                                                           \
            f32x4 sg[3];                                                      \
            _Pragma("unroll") for (int g = 0; g < 3; ++g) {                   \
                f32x4 a = ring[0][g];                                         \
                a += ring[1][g]; a += ring[2][g];                             \
                a += ring[3][g]; a += ring[4][g];                             \
                sg[g] = a * (1.0f / 125.0f);                                  \
            }                                                                 \
            float sv[12];                                                     \
            _Pragma("unroll") for (int g = 0; g < 3; ++g) {                   \
                sv[4*g+0] = sg[g].x; sv[4*g+1] = sg[g].y;                     \
                sv[4*g+2] = sg[g].z; sv[4*g+3] = sg[g].w;                     \
            }                                                                 \
            float mn = sv[0], tt = sv[0];                                     \
            _Pragma("unroll") for (int z = 1; z < 12; ++z) {                  \
                mn = fminf(mn, sv[z]); tt += sv[z];                           \
            }                                                                 \
            if (valid) {                                                      \
                _Pragma("unroll") for (int z = 0; z < 12; ++z)                \
                    Cout[(size_t)z * NNN + (unsigned)voxoff] = sv[z] - mn;    \
                lsum += tt * (1.0f / 12.0f) - mn;     /* mind_var */          \
                voxoff += NN;                                                 \
            }                                                                 \
        }                                                                     \
    }                                                                         \
} while (0)

    // warmup: fill ring slots 0..3 (box planes D0-2 .. D0+1, clamped)
    STEP(0, 0, false);
    STEP(1, 1, false);
    STEP(2, 2, false);
    STEP(3, 3, false);

    // main: its 4..steps-1; base ≡ 4 (mod 5) keeps ring slots compile-time
    for (int base = 4; base < steps; base += 5) {
        STEP(base + 0, 4, true);
        if (base + 1 < steps) STEP(base + 1, 0, true);
        if (base + 2 < steps) STEP(base + 2, 1, true);
        if (base + 3 < steps) STEP(base + 3, 2, true);
        if (base + 4 < steps) STEP(base + 4, 3, true);
    }
#undef STEP

    // block reduction of mind_var partial sum
    red[tid] = lsum;
    __syncthreads();
    for (int st = 256; st > 0; st >>= 1) {
        if (tid < st) red[tid] += red[tid + st];
        __syncthreads();
    }
    if (tid == 0) atomicAdd(acc, (double)red[0]);
}

// zero the accumulator
__global__ void k_zero(double* acc) {
    if (blockIdx.x == 0 && threadIdx.x == 0) *acc = 0.0;
}

// K3: in-place epilogue on d_out, float4-vectorized.
// mvar = mean_ch(mind), clip to [1e-3,1e3]*mean, exp.
__global__ __launch_bounds__(256) void k_exp(float* __restrict__ io,
                                             const double* __restrict__ acc) {
    int q = blockIdx.x * 256 + threadIdx.x;      // float4 index
    if (q >= NQ4) return;
    const float mv_mean = (float)(*acc * (1.0 / (double)NNN));
    const float lo = mv_mean * 0.001f, hi = mv_mean * 1000.0f;

    f32x4 v[NCH];
    f32x4 tot = (f32x4){0.0f, 0.0f, 0.0f, 0.0f};
    #pragma unroll
    for (int o = 0; o < NCH; ++o) {
        v[o] = *((const f32x4*)io + (size_t)o * NQ4 + q);
        tot += v[o];
    }
    f32x4 inv;
    #pragma unroll
    for (int k = 0; k < 4; ++k) {
        float mvar = tot[k] * (1.0f / 12.0f);
        mvar = fminf(fmaxf(mvar, lo), hi);
        inv[k] = 1.0f / mvar;
    }
    #pragma unroll
    for (int o = 0; o < NCH; ++o) {
        f32x4 rr;
        #pragma unroll
        for (int k = 0; k < 4; ++k)
            rr[k] = expf(-v[o][k] * inv[k]);
        *((f32x4*)io + (size_t)o * NQ4 + q) = rr;
    }
}

extern "C" void kernel_launch(void* const* d_in, const int* in_sizes, int n_in,
                              void* d_out, int out_size, void* d_ws, size_t ws_size,
                              hipStream_t stream) {
    const float* x = (const float*)d_in[0];
    float* out = (float*)d_out;                 // [12,130,130,130] f32
    double* acc = (double*)d_ws;

    k_zero <<<1, 64, 0, stream>>>(acc);
    k_fused<<<WT * HT * DSEGS, 512, 0, stream>>>(x, out, acc);   // 495 blocks
    k_exp  <<<(NQ4 + 255) / 256, 256, 0, stream>>>(out, acc);    // 2146 blocks
}